// Round 7
// baseline (224.305 us; speedup 1.0000x reference)
//
#include <hip/hip_runtime.h>

#define NB 256
#define NO 10
#define NI 1152
#define NK 8
#define ND 16
#define PCH 36    // chunks for pass0/acc
#define PIC 32    // NI / PCH
#define DCH 144   // chunks for dotsoft (IC=8)
#define DIC 8

typedef unsigned short u16;
typedef unsigned int u32;
typedef __attribute__((ext_vector_type(8))) short s8v;   // 8 bf16 = 4 VGPR (MFMA A/B frag)
typedef __attribute__((ext_vector_type(4))) float f4v;   // MFMA C/D frag
typedef __attribute__((ext_vector_type(4))) u32 u32x4;

__device__ __forceinline__ u16 f2bf(float f){
  u32 u = __float_as_uint(f);
  return (u16)((u + 0x7FFFu + ((u >> 16) & 1u)) >> 16);  // RNE
}
__device__ __forceinline__ float bf2f(u16 h){ return __uint_as_float(((u32)h) << 16); }
__device__ __forceinline__ u32 cvt_pk_bf16(float lo, float hi){
  u32 r;
  asm("v_cvt_pk_bf16_f32 %0, %1, %2" : "=v"(r) : "v"(lo), "v"(hi));
  return r;
}
__device__ __forceinline__ s8v zero8(){
  s8v z;
  #pragma unroll
  for (int j = 0; j < 8; ++j) z[j] = 0;
  return z;
}

// Last-block-per-o fixup: reduce P[o,:,ch,:] over ch -> Sbt (or squash -> out when LAST).
// Counters self-reset so the same array serves all three uses per call, deterministically.
__device__ __forceinline__ void fixup_reduce(bool last, const float* __restrict__ P,
                                             u16* __restrict__ Sbt, float* __restrict__ out,
                                             int o, u32* __restrict__ cnt){
  __shared__ int flag;
  if (threadIdx.x == 0){
    u32 old = __hip_atomic_fetch_add(&cnt[o], 1u, __ATOMIC_ACQ_REL, __HIP_MEMORY_SCOPE_AGENT);
    flag = (old == PCH - 1);
  }
  __syncthreads();
  if (!flag) return;
  int b = threadIdx.x;
  float s[ND], s2 = 0.f;
  #pragma unroll
  for (int d = 0; d < ND; ++d){
    const float* p = P + ((size_t)o * ND + d) * PCH * NB + b;
    float a0 = 0.f, a1 = 0.f, a2 = 0.f, a3 = 0.f;
    #pragma unroll
    for (int ch = 0; ch < PCH; ch += 4){
      a0 += p[(size_t)ch * NB];
      a1 += p[(size_t)(ch + 1) * NB];
      a2 += p[(size_t)(ch + 2) * NB];
      a3 += p[(size_t)(ch + 3) * NB];
    }
    s[d] = (a0 + a1) + (a2 + a3);
    s2 = fmaf(s[d], s[d], s2);
  }
  if (last){
    float sc = (s2 / (1.f + s2)) / (sqrtf(s2) + 1e-8f);
    #pragma unroll
    for (int q = 0; q < 4; ++q){
      float4 v = make_float4(s[4*q] * sc, s[4*q+1] * sc, s[4*q+2] * sc, s[4*q+3] * sc);
      *(float4*)(out + ((size_t)b * NO + o) * ND + 4 * q) = v;
    }
  } else {
    u32 pk[8];
    #pragma unroll
    for (int j = 0; j < 8; ++j) pk[j] = cvt_pk_bf16(s[2*j], s[2*j+1]);
    uint4* dst = (uint4*)(Sbt + ((size_t)o * NB + b) * ND);
    dst[0] = make_uint4(pk[0], pk[1], pk[2], pk[3]);
    dst[1] = make_uint4(pk[4], pk[5], pk[6], pk[7]);
  }
  if (threadIdx.x == 0)
    __hip_atomic_store(&cnt[o], 0u, __ATOMIC_RELAXED, __HIP_MEMORY_SCOPE_AGENT);
}

// One-time: xbf[i][b][k] = bf16(x[b][i][k]); Wb = bf16(W) [o][i][d][k]; WTb [o][i][k][d]; cnt=0
__global__ __launch_bounds__(256) void k_prep(const float* __restrict__ x,
                                              const float* __restrict__ W,
                                              u16* __restrict__ xbf,
                                              u16* __restrict__ Wb,
                                              u16* __restrict__ WTb,
                                              u32* __restrict__ cnt){
  int t = blockIdx.x * 256 + threadIdx.x;
  if (t < NO) cnt[t] = 0;
  const int NX = NI * NB * NK;
  for (int idx = t; idx < NX; idx += gridDim.x * 256){
    int k = idx & 7, b = (idx >> 3) & (NB - 1), i = idx >> 11;   // NB*NK = 2048
    xbf[idx] = f2bf(x[((size_t)b * NI + i) * NK + k]);
  }
  const int NW = NO * NI * ND * NK;
  for (int idx = t; idx < NW; idx += gridDim.x * 256){
    u16 h = f2bf(W[idx]);
    Wb[idx] = h;
    int k = idx & 7, d = (idx >> 3) & 15, oi = idx >> 7;
    WTb[((size_t)oi * NK + k) * ND + d] = h;
  }
}

// Iter0: per-i u-tiles via MFMA. Epilogue: usq; P[o,d,ch,b] = 0.1*sum_i u; fixup -> Sbt
__global__ __launch_bounds__(256) void k_pass0(const u16* __restrict__ xbf,
                                               const u16* __restrict__ Wb,
                                               float* __restrict__ usq,
                                               float* __restrict__ P,
                                               u16* __restrict__ Sbt,
                                               u32* __restrict__ cnt){
  int ch = blockIdx.x, o = blockIdx.y, i0 = ch * PIC;
  int w = threadIdx.x >> 6, l = threadIdx.x & 63, g = l >> 4, col = l & 15;
  float s0[4][4];
  #pragma unroll
  for (int bt = 0; bt < 4; ++bt){
    #pragma unroll
    for (int j = 0; j < 4; ++j) s0[bt][j] = 0.f;
  }
  for (int ii = 0; ii < PIC; ++ii){
    int i = i0 + ii;
    s8v a = zero8();
    if (g == 0)  // A[d=col][k=j]
      a = *(const s8v*)(Wb + ((size_t)(o * NI + i) * ND + col) * NK);
    #pragma unroll
    for (int bt = 0; bt < 4; ++bt){
      int b = (w * 4 + bt) * 16 + col;
      s8v bf = zero8();
      if (g == 0)  // B[k=j][n=col] = x[i][b][j] (contiguous in b)
        bf = *(const s8v*)(xbf + ((size_t)i * NB + b) * NK);
      f4v c = {0.f, 0.f, 0.f, 0.f};
      c = __builtin_amdgcn_mfma_f32_16x16x32_bf16(a, bf, c, 0, 0, 0);
      float uq = c[0]*c[0] + c[1]*c[1] + c[2]*c[2] + c[3]*c[3];
      uq += __shfl_xor(uq, 16);
      uq += __shfl_xor(uq, 32);
      if (g == 0) usq[((size_t)o * NI + i) * NB + b] = uq;
      #pragma unroll
      for (int j = 0; j < 4; ++j) s0[bt][j] += c[j];
    }
  }
  #pragma unroll
  for (int bt = 0; bt < 4; ++bt){
    int b = (w * 4 + bt) * 16 + col;
    #pragma unroll
    for (int j = 0; j < 4; ++j)
      P[(((size_t)o * ND + (4 * g + j)) * PCH + ch) * NB + b] = 0.1f * s0[bt][j];
  }
  fixup_reduce(false, P, Sbt, nullptr, o, cnt);
}

// Fused dot (MFMA T = W^T S) + db + L-update + softmax -> C
template<bool FIRST>
__global__ __launch_bounds__(256) void k_dotsoft(const u16* __restrict__ xbf,
                                                 const u16* __restrict__ WTb,
                                                 const u16* __restrict__ Sbt,
                                                 const float* __restrict__ usq,
                                                 float* __restrict__ L,
                                                 float* __restrict__ C){
  int ch = blockIdx.x, ibase = ch * DIC;
  int w = threadIdx.x >> 6, l = threadIdx.x & 63, g = l >> 4, col = l & 15;
  int b = (blockIdx.y * 4 + w) * 16 + col;
  // Hoist B-frags (S tiles); |S|^2 from the frags via shfl (g0:d0-7, g1:d8-15)
  s8v sb[NO];
  float s2v[NO];
  #pragma unroll
  for (int o = 0; o < NO; ++o){
    sb[o] = zero8();
    if (g < 2)
      sb[o] = *(const s8v*)(Sbt + ((size_t)o * NB + b) * ND + 8 * g);
    float s2 = 0.f;
    #pragma unroll
    for (int j = 0; j < 8; ++j){
      float v = bf2f((u16)sb[o][j]);
      s2 = fmaf(v, v, s2);
    }
    s2 += __shfl_xor(s2, 16);
    s2 += __shfl_xor(s2, 32);
    s2v[o] = s2;
  }
  for (int ip = 0; ip < DIC / 2; ++ip){
    int i0 = ibase + 2 * ip;
    int i = i0 + (g >> 1);          // this lane's i for epilogue rows
    int kb = 4 * (g & 1);
    ushort4 xq = *(const ushort4*)(xbf + ((size_t)i * NB + b) * NK + kb);
    float dots[NO];
    #pragma unroll
    for (int o = 0; o < NO; ++o){
      s8v a = zero8();
      if (g < 2){                   // A[r=col][kd=8g+j] = WTb[o][i(r)][k(r)][d]
        int ia = i0 + (col >> 3), ka = col & 7;
        a = *(const s8v*)(WTb + (((size_t)(o * NI + ia)) * NK + ka) * ND + 8 * g);
      }
      f4v c = {0.f, 0.f, 0.f, 0.f};
      c = __builtin_amdgcn_mfma_f32_16x16x32_bf16(a, sb[o], c, 0, 0, 0);
      // C rows 4g+j = (i = i0 + (row>>3), k = row&7); matches (i, kb..kb+3)
      float p = c[0] * bf2f(xq.x) + c[1] * bf2f(xq.y)
              + c[2] * bf2f(xq.z) + c[3] * bf2f(xq.w);
      p += __shfl_xor(p, 16);       // g0+g1 -> dot(i0); g2+g3 -> dot(i1)
      dots[o] = p;
    }
    float lg[NO];
    #pragma unroll
    for (int o = 0; o < NO; ++o){
      float us = usq[((size_t)o * NI + i) * NB + b];
      float t2 = fmaxf(s2v[o] - 2.f * dots[o] + us, 0.f);
      float ut = dots[o] - us;
      float db = (t2 / (1.f + t2)) * ut / (sqrtf(t2) + 1e-8f);
      float lo = FIRST ? db : (L[((size_t)o * NI + i) * NB + b] + db);
      if (FIRST && ((g & 1) == 0)) L[((size_t)o * NI + i) * NB + b] = lo;
      lg[o] = lo;
    }
    float m = lg[0];
    #pragma unroll
    for (int o = 1; o < NO; ++o) m = fmaxf(m, lg[o]);
    float den = 0.f;
    #pragma unroll
    for (int o = 0; o < NO; ++o){ lg[o] = __expf(lg[o] - m); den += lg[o]; }
    float inv = 1.f / den;
    if ((g & 1) == 0){
      #pragma unroll
      for (int o = 0; o < NO; ++o)
        C[((size_t)o * NI + i) * NB + b] = lg[o] * inv;
    }
  }
}

// Dense split-K GEMM: P[o,d,ch,b] = sum_{i,k} W[o,i,d,k]*(c*x)[b,i,k]; fixup -> Sbt / out
template<bool LAST>
__global__ __launch_bounds__(256) void k_acc(const u16* __restrict__ xbf,
                                             const u16* __restrict__ Wb,
                                             const float* __restrict__ C,
                                             float* __restrict__ P,
                                             u16* __restrict__ Sbt,
                                             float* __restrict__ out,
                                             u32* __restrict__ cnt){
  int ch = blockIdx.x, o = blockIdx.y, i0 = ch * PIC;
  int w = threadIdx.x >> 6, l = threadIdx.x & 63, g = l >> 4, col = l & 15;
  f4v cacc[4];
  #pragma unroll
  for (int bt = 0; bt < 4; ++bt) cacc[bt] = (f4v){0.f, 0.f, 0.f, 0.f};
  for (int kt = 0; kt < PIC / 4; ++kt){
    int il = i0 + kt * 4 + g;       // this lane's i (K packs 4 i's)
    // A[d=col][k=8g+j] = W[o][il][col][j]
    s8v a = *(const s8v*)(Wb + ((size_t)(o * NI + il) * ND + col) * NK);
    #pragma unroll
    for (int bt = 0; bt < 4; ++bt){
      int b = (w * 4 + bt) * 16 + col;
      float cw = C[((size_t)o * NI + il) * NB + b];
      s8v xv = *(const s8v*)(xbf + ((size_t)il * NB + b) * NK);
      u32x4 q;
      #pragma unroll
      for (int j = 0; j < 4; ++j)
        q[j] = cvt_pk_bf16(bf2f((u16)xv[2*j]) * cw, bf2f((u16)xv[2*j+1]) * cw);
      s8v bb = __builtin_bit_cast(s8v, q);
      cacc[bt] = __builtin_amdgcn_mfma_f32_16x16x32_bf16(a, bb, cacc[bt], 0, 0, 0);
    }
  }
  #pragma unroll
  for (int bt = 0; bt < 4; ++bt){
    int b = (w * 4 + bt) * 16 + col;
    #pragma unroll
    for (int j = 0; j < 4; ++j)
      P[(((size_t)o * ND + (4 * g + j)) * PCH + ch) * NB + b] = cacc[bt][j];
  }
  fixup_reduce(LAST, P, Sbt, out, o, cnt);
}

extern "C" void kernel_launch(void* const* d_in, const int* in_sizes, int n_in,
                              void* d_out, int out_size, void* d_ws, size_t ws_size,
                              hipStream_t stream){
  const float* x = (const float*)d_in[0];
  // d_in[1] (y) unused by the reference computation.
  const float* W = (const float*)d_in[2];
  float* out = (float*)d_out;
  char* ws = (char*)d_ws;

  const size_t xbf_b = (size_t)NI * NB * NK * sizeof(u16);            // 4.7 MB
  const size_t Wb_b  = (size_t)NO * NI * ND * NK * sizeof(u16);       // 2.95 MB
  const size_t usq_b = (size_t)NO * NI * NB * sizeof(float);          // 11.8 MB
  const size_t P_b   = (size_t)NO * ND * PCH * NB * sizeof(float);    // 5.9 MB
  const size_t Sbt_b = (size_t)NO * NB * ND * sizeof(u16);            // 80 KB
  const size_t cnt_b = 256;                                           // 10 u32, padded

  size_t off = 0;
  u16*   xbf = (u16*)(ws + off);   off += xbf_b;
  u16*   Wb  = (u16*)(ws + off);   off += Wb_b;
  u16*   WTb = (u16*)(ws + off);   off += Wb_b;
  float* usq = (float*)(ws + off); off += usq_b;
  float* L   = (float*)(ws + off); off += usq_b;
  float* C   = (float*)(ws + off); off += usq_b;
  float* P   = (float*)(ws + off); off += P_b;
  u16*   Sbt = (u16*)(ws + off);   off += Sbt_b;
  u32*   cnt = (u32*)(ws + off);   off += cnt_b;
  (void)ws_size; (void)in_sizes; (void)n_in; (void)out_size;

  k_prep<<<dim3(1024), 256, 0, stream>>>(x, W, xbf, Wb, WTb, cnt);

  // iter 0: uniform c = 0.1 -> S0 (+fixup -> Sbt), usq
  k_pass0<<<dim3(PCH, NO), 256, 0, stream>>>(xbf, Wb, usq, P, Sbt, cnt);
  k_dotsoft<true><<<dim3(DCH, 4), 256, 0, stream>>>(xbf, WTb, Sbt, usq, L, C);

  // iter 1
  k_acc<false><<<dim3(PCH, NO), 256, 0, stream>>>(xbf, Wb, C, P, Sbt, out, cnt);
  k_dotsoft<false><<<dim3(DCH, 4), 256, 0, stream>>>(xbf, WTb, Sbt, usq, L, C);

  // iter 2 (final accumulation; fixup does squash -> out)
  k_acc<true><<<dim3(PCH, NO), 256, 0, stream>>>(xbf, Wb, C, P, Sbt, out, cnt);
}